// Round 2
// baseline (322.246 us; speedup 1.0000x reference)
//
#include <hip/hip_runtime.h>
#include <hip/hip_bf16.h>

// CovPooling: B=4096 graphs, n=512 nodes/graph, D=64 features.
// cov = X^T X / n - mu mu^T, upper triangle packed (2080 per graph).
// R2: CHUNK 256->128 (8 blocks/CU), 8-deep load ILP, cvt_pk bf16 casts,
//     b128 LDS writes.

#define DD      64
#define NPG     512
#define CHUNK   128
#define XSTRIDE 136   // ushorts per Xt row: 128 nodes + 8 pad = 272 B (16B-aligned)

typedef __bf16 bf16x8 __attribute__((ext_vector_type(8)));
typedef float  f32x4  __attribute__((ext_vector_type(4)));

__global__ __launch_bounds__(256, 8)
void cov_pool_kernel(const float* __restrict__ X, float* __restrict__ out) {
  // Transposed bf16 tile: Xt[dim][node_in_chunk], row stride 136 ushorts.
  __shared__ __align__(16) unsigned short Xt[DD * XSTRIDE];
  __shared__ float sumbuf[4][DD];
  __shared__ float mu[DD];

  const int t    = threadIdx.x;
  const int lane = t & 63;
  const int w    = t >> 6;            // wave id 0..3
  const long g   = blockIdx.x;
  const float* Xg = X + g * (long)(NPG * DD) + lane;  // lane = dim column

  const int dimq = lane & 15;         // fragment row/col within 16-tile
  const int kgrp = (lane >> 4) * 8;   // fragment k-group base

  float csum = 0.f;                   // fp32 column sum for dim `lane`
  f32x4 acc[4];
  f32x4 zero = {0.f, 0.f, 0.f, 0.f};
  acc[0] = zero; acc[1] = zero; acc[2] = zero; acc[3] = zero;

  for (int c = 0; c < NPG / CHUNK; ++c) {
    // ---- stage CHUNK nodes: coalesced dword column loads -> bf16 transposed LDS.
    // Each iter: wave reads 8 node rows (8 x 256B coalesced wave-loads, all
    // immediate offsets off one base -> 8 loads in flight), packs to bf16x8,
    // one ds_write_b128 along the node dim.
    #pragma unroll
    for (int it = 0; it < CHUNK / 32; ++it) {
      const int nc = it * 32 + w * 8;              // in-chunk node base (8 nodes)
      const float* p = Xg + (long)(c * CHUNK + nc) * DD;
      float f[8];
      #pragma unroll
      for (int k = 0; k < 8; ++k) f[k] = p[k * DD];
      csum += ((f[0] + f[1]) + (f[2] + f[3])) + ((f[4] + f[5]) + (f[6] + f[7]));
      bf16x8 b;
      #pragma unroll
      for (int k = 0; k < 8; ++k) b[k] = (__bf16)f[k];  // v_cvt_pk_bf16_f32
      *(bf16x8*)&Xt[lane * XSTRIDE + nc] = b;
    }
    __syncthreads();

    // ---- MFMA accumulate over this chunk (K = 128, steps of 32) ----
    #pragma unroll
    for (int kk = 0; kk < CHUNK / 32; ++kk) {
      const int kb = kk * 32 + kgrp;
      const bf16x8 A   = *(const bf16x8*)&Xt[(w * 16 + dimq) * XSTRIDE + kb];
      const bf16x8 fb0 = *(const bf16x8*)&Xt[( 0 + dimq) * XSTRIDE + kb];
      const bf16x8 fb1 = *(const bf16x8*)&Xt[(16 + dimq) * XSTRIDE + kb];
      const bf16x8 fb2 = *(const bf16x8*)&Xt[(32 + dimq) * XSTRIDE + kb];
      const bf16x8 fb3 = *(const bf16x8*)&Xt[(48 + dimq) * XSTRIDE + kb];
      if (w <= 0) acc[0] = __builtin_amdgcn_mfma_f32_16x16x32_bf16(A, fb0, acc[0], 0, 0, 0);
      if (w <= 1) acc[1] = __builtin_amdgcn_mfma_f32_16x16x32_bf16(A, fb1, acc[1], 0, 0, 0);
      if (w <= 2) acc[2] = __builtin_amdgcn_mfma_f32_16x16x32_bf16(A, fb2, acc[2], 0, 0, 0);
      acc[3] = __builtin_amdgcn_mfma_f32_16x16x32_bf16(A, fb3, acc[3], 0, 0, 0);
    }
    __syncthreads();   // protect Xt before next chunk's staging
  }

  // ---- column sums -> mean ----
  sumbuf[w][lane] = csum;
  __syncthreads();
  if (t < DD) {
    mu[t] = (sumbuf[0][t] + sumbuf[1][t] + sumbuf[2][t] + sumbuf[3][t]) * (1.f / NPG);
  }
  __syncthreads();

  // ---- epilogue: cov = acc/n - mu_i mu_j, write packed upper triangle ----
  const float inv_n = 1.f / NPG;
  float* og = out + g * 2080L;
  const int rbase = w * 16 + (lane >> 4) * 4;   // C row = (lane>>4)*4 + reg
  #pragma unroll
  for (int tn = 0; tn < 4; ++tn) {
    if (tn < w) continue;                       // only upper-triangle tiles
    const int j = tn * 16 + dimq;               // C col = lane & 15
    const float muj = mu[j];
    #pragma unroll
    for (int r = 0; r < 4; ++r) {
      const int i = rbase + r;
      if (j >= i) {
        const float v = acc[tn][r] * inv_n - mu[i] * muj;
        og[i * DD - (i * (i - 1)) / 2 + (j - i)] = v;
      }
    }
  }
}

extern "C" void kernel_launch(void* const* d_in, const int* in_sizes, int n_in,
                              void* d_out, int out_size, void* d_ws, size_t ws_size,
                              hipStream_t stream) {
  const float* X = (const float*)d_in[0];
  float* out = (float*)d_out;
  const int N = in_sizes[0] / DD;     // total nodes
  const int B = N / NPG;              // graphs
  cov_pool_kernel<<<dim3(B), dim3(256), 0, stream>>>(X, out);
}

// Round 3
// 221.557 us; speedup vs baseline: 1.4545x; 1.4545x over previous
//
#include <hip/hip_runtime.h>
#include <hip/hip_bf16.h>

// CovPooling: B=4096 graphs, n=512 nodes/graph, D=64 features.
// cov = X^T X / n - mu mu^T, upper triangle packed (2080 per graph).
// R3: back to no-spill regs (launch_bounds(256,4)); double-buffered LDS with
//     ONE raw barrier per chunk (lgkmcnt-only, loads stay in flight across
//     it); next-chunk loads issued before the barrier; diag A-frag reuse.

#define DD      64
#define NPG     512
#define CHUNK   128
#define NCHUNK  (NPG / CHUNK)
#define XSTRIDE 136   // ushorts per Xt row: 128 nodes + 8 pad = 272 B

typedef __bf16 bf16x8 __attribute__((ext_vector_type(8)));
typedef float  f32x4  __attribute__((ext_vector_type(4)));

__global__ __launch_bounds__(256, 4)
void cov_pool_kernel(const float* __restrict__ X, float* __restrict__ out) {
  __shared__ __align__(16) unsigned short Xt[2][DD * XSTRIDE];
  __shared__ float sumbuf[4][DD];
  __shared__ float mu[DD];

  const int t    = threadIdx.x;
  const int lane = t & 63;
  const int w    = t >> 6;            // wave id 0..3
  const long g   = blockIdx.x;
  const float* Xg = X + g * (long)(NPG * DD) + lane;  // lane = dim column

  const int dimq = lane & 15;         // fragment row/col within 16-tile
  const int kgrp = (lane >> 4) * 8;   // fragment k-group base

  float csum = 0.f;
  f32x4 acc[4];
  f32x4 zero = {0.f, 0.f, 0.f, 0.f};
  acc[0] = zero; acc[1] = zero; acc[2] = zero; acc[3] = zero;

  float f[NCHUNK == 0 ? 1 : 4][8];    // fully static-indexed (unrolled)

  // ---- prologue: issue chunk 0's loads (32 coalesced 256B wave-loads) ----
  #pragma unroll
  for (int it = 0; it < CHUNK / 32; ++it) {
    const float* p = Xg + (long)(it * 32 + w * 8) * DD;
    #pragma unroll
    for (int k = 0; k < 8; ++k) f[it][k] = p[k * DD];
  }

  #pragma unroll
  for (int c = 0; c < NCHUNK; ++c) {
    unsigned short* buf = Xt[c & 1];

    // ---- pack chunk c -> bf16 transposed LDS (consumes f, waits vmcnt) ----
    #pragma unroll
    for (int it = 0; it < CHUNK / 32; ++it) {
      csum += ((f[it][0] + f[it][1]) + (f[it][2] + f[it][3]))
            + ((f[it][4] + f[it][5]) + (f[it][6] + f[it][7]));
      bf16x8 b;
      #pragma unroll
      for (int k = 0; k < 8; ++k) b[k] = (__bf16)f[it][k];
      *(bf16x8*)&buf[lane * XSTRIDE + it * 32 + w * 8] = b;
    }

    // ---- issue chunk c+1's loads; they stay in flight across the barrier ----
    if (c + 1 < NCHUNK) {
      #pragma unroll
      for (int it = 0; it < CHUNK / 32; ++it) {
        const float* p = Xg + (long)((c + 1) * CHUNK + it * 32 + w * 8) * DD;
        #pragma unroll
        for (int k = 0; k < 8; ++k) f[it][k] = p[k * DD];
      }
    }

    // ---- order ds_writes only (no vmcnt drain), then barrier ----
    asm volatile("s_waitcnt lgkmcnt(0)" ::: "memory");
    __builtin_amdgcn_s_barrier();

    // ---- MFMA accumulate over chunk c (K = 128, steps of 32) ----
    #pragma unroll
    for (int kk = 0; kk < CHUNK / 32; ++kk) {
      const int kb = kk * 32 + kgrp;
      const bf16x8 fb0 = *(const bf16x8*)&buf[( 0 + dimq) * XSTRIDE + kb];
      const bf16x8 fb1 = *(const bf16x8*)&buf[(16 + dimq) * XSTRIDE + kb];
      const bf16x8 fb2 = *(const bf16x8*)&buf[(32 + dimq) * XSTRIDE + kb];
      const bf16x8 fb3 = *(const bf16x8*)&buf[(48 + dimq) * XSTRIDE + kb];
      bf16x8 A;                        // diag tile: A == fb[w] (uniform branch)
      if      (w == 0) A = fb0;
      else if (w == 1) A = fb1;
      else if (w == 2) A = fb2;
      else             A = fb3;
      if (w <= 0) acc[0] = __builtin_amdgcn_mfma_f32_16x16x32_bf16(A, fb0, acc[0], 0, 0, 0);
      if (w <= 1) acc[1] = __builtin_amdgcn_mfma_f32_16x16x32_bf16(A, fb1, acc[1], 0, 0, 0);
      if (w <= 2) acc[2] = __builtin_amdgcn_mfma_f32_16x16x32_bf16(A, fb2, acc[2], 0, 0, 0);
      acc[3] = __builtin_amdgcn_mfma_f32_16x16x32_bf16(A, fb3, acc[3], 0, 0, 0);
    }
    // no second barrier: next chunk writes the OTHER buffer; the single
    // barrier per chunk separates read(buf[c&1]) from its re-write at c+2.
  }

  // ---- column sums -> mean ----
  sumbuf[w][lane] = csum;
  __syncthreads();
  if (t < DD) {
    mu[t] = (sumbuf[0][t] + sumbuf[1][t] + sumbuf[2][t] + sumbuf[3][t]) * (1.f / NPG);
  }
  __syncthreads();

  // ---- epilogue: cov = acc/n - mu_i mu_j, write packed upper triangle ----
  const float inv_n = 1.f / NPG;
  float* og = out + g * 2080L;
  const int rbase = w * 16 + (lane >> 4) * 4;   // C row = (lane>>4)*4 + reg
  #pragma unroll
  for (int tn = 0; tn < 4; ++tn) {
    if (tn < w) continue;                       // only upper-triangle tiles
    const int j = tn * 16 + dimq;               // C col = lane & 15
    const float muj = mu[j];
    #pragma unroll
    for (int r = 0; r < 4; ++r) {
      const int i = rbase + r;
      if (j >= i) {
        const float v = acc[tn][r] * inv_n - mu[i] * muj;
        og[i * DD - (i * (i - 1)) / 2 + (j - i)] = v;
      }
    }
  }
}

extern "C" void kernel_launch(void* const* d_in, const int* in_sizes, int n_in,
                              void* d_out, int out_size, void* d_ws, size_t ws_size,
                              hipStream_t stream) {
  const float* X = (const float*)d_in[0];
  float* out = (float*)d_out;
  const int N = in_sizes[0] / DD;     // total nodes
  const int B = N / NPG;              // graphs
  cov_pool_kernel<<<dim3(B), dim3(256), 0, stream>>>(X, out);
}

// Round 4
// 116.740 us; speedup vs baseline: 2.7604x; 1.8979x over previous
//
#include <hip/hip_runtime.h>
#include <hip/hip_bf16.h>

// CovPooling: B=4096 graphs, n=512 nodes/graph, D=64 features.
// cov = X^T X / n - mu mu^T, upper triangle packed (2080 per graph).
// R4: one wave per graph. Zero LDS, zero barriers. Fragments loaded directly
//     from global with per-lane addresses (A-frag == B-frag content for
//     symmetric product), bf16 cvt in-register, 10 upper-triangle MFMAs.
//     Pure streaming: every wave keeps a 32-load window in flight.

#define DD   64
#define NPG  512
#define NIT  (NPG / 32)   // 16 K-steps of 32 nodes

typedef __bf16 bf16x8 __attribute__((ext_vector_type(8)));
typedef float  f32x4  __attribute__((ext_vector_type(4)));

__global__ __launch_bounds__(256, 4)
void cov_pool_kernel(const float* __restrict__ X, float* __restrict__ out,
                     int n_graphs) {
  const int lane = threadIdx.x & 63;
  const int w    = threadIdx.x >> 6;
  const long g   = (long)blockIdx.x * 4 + w;
  if (g >= n_graphs) return;

  const int dimq = lane & 15;          // fragment row/col within 16-tile
  const int kgrp = (lane >> 4) * 8;    // fragment k-group base (nodes)

  // lane's load base: node (kgrp + j), dim (16*t + dimq)
  const float* base = X + g * (long)(NPG * DD) + (long)kgrp * DD + dimq;

  f32x4 z = {0.f, 0.f, 0.f, 0.f};
  f32x4 a00=z,a01=z,a02=z,a03=z,a11=z,a12=z,a13=z,a22=z,a23=z,a33=z;
  float cs0=0.f, cs1=0.f, cs2=0.f, cs3=0.f;

  float f0[8], f1[8], f2[8], f3[8];
  #pragma unroll
  for (int j = 0; j < 8; ++j) {        // prologue: k-step 0 (32 dword loads)
    f0[j] = base[j*DD +  0];
    f1[j] = base[j*DD + 16];
    f2[j] = base[j*DD + 32];
    f3[j] = base[j*DD + 48];
  }

  #pragma unroll 1
  for (int it = 0; it < NIT; ++it) {
    bf16x8 b0, b1, b2, b3;
    #pragma unroll
    for (int j = 0; j < 8; ++j) {      // exact fp32 column sums + bf16 cvt
      cs0 += f0[j]; b0[j] = (__bf16)f0[j];
      cs1 += f1[j]; b1[j] = (__bf16)f1[j];
      cs2 += f2[j]; b2[j] = (__bf16)f2[j];
      cs3 += f3[j]; b3[j] = (__bf16)f3[j];
    }
    if (it + 1 < NIT) {                // prefetch next k-step; stays in flight
      const float* p = base + (long)(it + 1) * 32 * DD;
      #pragma unroll
      for (int j = 0; j < 8; ++j) {
        f0[j] = p[j*DD +  0];
        f1[j] = p[j*DD + 16];
        f2[j] = p[j*DD + 32];
        f3[j] = p[j*DD + 48];
      }
    }
    // 10 upper-triangle tiles; A-frag content == B-frag content
    a00 = __builtin_amdgcn_mfma_f32_16x16x32_bf16(b0, b0, a00, 0, 0, 0);
    a01 = __builtin_amdgcn_mfma_f32_16x16x32_bf16(b0, b1, a01, 0, 0, 0);
    a02 = __builtin_amdgcn_mfma_f32_16x16x32_bf16(b0, b2, a02, 0, 0, 0);
    a03 = __builtin_amdgcn_mfma_f32_16x16x32_bf16(b0, b3, a03, 0, 0, 0);
    a11 = __builtin_amdgcn_mfma_f32_16x16x32_bf16(b1, b1, a11, 0, 0, 0);
    a12 = __builtin_amdgcn_mfma_f32_16x16x32_bf16(b1, b2, a12, 0, 0, 0);
    a13 = __builtin_amdgcn_mfma_f32_16x16x32_bf16(b1, b3, a13, 0, 0, 0);
    a22 = __builtin_amdgcn_mfma_f32_16x16x32_bf16(b2, b2, a22, 0, 0, 0);
    a23 = __builtin_amdgcn_mfma_f32_16x16x32_bf16(b2, b3, a23, 0, 0, 0);
    a33 = __builtin_amdgcn_mfma_f32_16x16x32_bf16(b3, b3, a33, 0, 0, 0);
  }

  // ---- mean: reduce lane-group partials (exact fp32), broadcast ----
  cs0 += __shfl_xor(cs0, 16, 64); cs0 += __shfl_xor(cs0, 32, 64);
  cs1 += __shfl_xor(cs1, 16, 64); cs1 += __shfl_xor(cs1, 32, 64);
  cs2 += __shfl_xor(cs2, 16, 64); cs2 += __shfl_xor(cs2, 32, 64);
  cs3 += __shfl_xor(cs3, 16, 64); cs3 += __shfl_xor(cs3, 32, 64);
  const float inv_n = 1.f / NPG;
  const float mu0 = cs0 * inv_n;   // lane holds mu[16*t + dimq]
  const float mu1 = cs1 * inv_n;
  const float mu2 = cs2 * inv_n;
  const float mu3 = cs3 * inv_n;

  const int rl = (lane >> 4) * 4;      // C row base within 16-tile
  float mur0[4], mur1[4], mur2[4], mur3[4];
  #pragma unroll
  for (int r = 0; r < 4; ++r) {        // mu[row] for each row this lane owns
    mur0[r] = __shfl(mu0, rl + r, 64);
    mur1[r] = __shfl(mu1, rl + r, 64);
    mur2[r] = __shfl(mu2, rl + r, 64);
    mur3[r] = __shfl(mu3, rl + r, 64);
  }

  // ---- epilogue: cov = acc/n - mu_i mu_j, packed upper triangle ----
  float* og = out + g * 2080L;
  auto wtile = [&](int tr, int tc, const f32x4& A, const float* MR, float MC,
                   bool diag) {
    const int j = tc * 16 + dimq;
    #pragma unroll
    for (int r = 0; r < 4; ++r) {
      const int i = tr * 16 + rl + r;
      if (!diag || j >= i) {
        og[i * DD - (i * (i - 1)) / 2 + (j - i)] = A[r] * inv_n - MR[r] * MC;
      }
    }
  };
  wtile(0, 0, a00, mur0, mu0, true);
  wtile(0, 1, a01, mur0, mu1, false);
  wtile(0, 2, a02, mur0, mu2, false);
  wtile(0, 3, a03, mur0, mu3, false);
  wtile(1, 1, a11, mur1, mu1, true);
  wtile(1, 2, a12, mur1, mu2, false);
  wtile(1, 3, a13, mur1, mu3, false);
  wtile(2, 2, a22, mur2, mu2, true);
  wtile(2, 3, a23, mur2, mu3, false);
  wtile(3, 3, a33, mur3, mu3, true);
}

extern "C" void kernel_launch(void* const* d_in, const int* in_sizes, int n_in,
                              void* d_out, int out_size, void* d_ws, size_t ws_size,
                              hipStream_t stream) {
  const float* X = (const float*)d_in[0];
  float* out = (float*)d_out;
  const int N = in_sizes[0] / DD;     // total nodes
  const int B = N / NPG;              // graphs
  cov_pool_kernel<<<dim3((B + 3) / 4), dim3(256), 0, stream>>>(X, out, B);
}